// Round 6
// baseline (669.517 us; speedup 1.0000x reference)
//
#include <hip/hip_runtime.h>

// Problem constants (from reference): B=2048, N=1024, C=128, M=64
constexpr int kB  = 2048;
constexpr int kN  = 1024;
constexpr int kC  = 128;
constexpr int kM  = 64;
constexpr int kC4 = kC / 4;    // float4 chunks per row = 32

constexpr int RPB   = 64;            // rows per block (== 64 -> u64 bitmap)
constexpr int BPB   = kN / RPB;      // row-blocks per batch = 16
constexpr int ITEMS = RPB * kC4 / 256;  // float4 items per thread = 8

using f4 = __attribute__((ext_vector_type(4))) float;

// ---------------------------------------------------------------------------
// Fused erase-add gate — barrier-free, LDS-free, gated rare path.
// One block = 64 rows of one batch; each wave fully independent:
//  - lane m holds indices[b][m]; ballot -> SGPR mask of locally-landing slots;
//  - short uniform loop (ctz + readlane) builds a u64 bitmap of indexed rows;
//  - hot path: 8 unrolled float4 loads, predicated OFF for indexed rows
//    (they're fully overwritten -> don't fetch), then 8 coalesced stores;
//    no barrier -> stores overlap outstanding loads via counted vmcnt;
//  - rare path (~6% of half-waves): walk the ballot mask (avg ~4 bits),
//    broadcast idx[m] with __builtin_amdgcn_readlane — v_readlane IGNORES
//    EXEC (ISA §12), so it is safe inside this divergent branch (the R5 bug:
//    __shfl -> ds_bpermute from an inactive lane is undefined). Accumulate
//    matching tar rows in slot order (duplicates sum; erase zeroes src).
// Every output element is written exactly once per call (deterministic).
// ---------------------------------------------------------------------------
__global__ __launch_bounds__(256) void eag_fused(const f4* __restrict__ src,
                                                 const f4* __restrict__ tar,
                                                 const int* __restrict__ indices,
                                                 f4* __restrict__ out) {
    const int bid  = blockIdx.x;
    const int b    = bid >> 4;                 // / BPB
    const int row0 = (bid & (BPB - 1)) * RPB;
    const int tid  = threadIdx.x;
    const int lane = tid & 63;

    // Per-wave index bookkeeping, register-resident.
    const int my_idx = indices[b * kM + lane];
    const int rel    = my_idx - row0;
    const bool local = (rel >= 0) && (rel < RPB);
    const unsigned long long lmask = __ballot(local);

    // Row bitmap (bit r = row row0+r is indexed): uniform loop, all lanes on.
    unsigned long long bitmap = 0;
    for (unsigned long long mm = lmask; mm; mm &= mm - 1) {
        const int m  = (int)__builtin_ctzll(mm);          // uniform slot id
        const int rm = __builtin_amdgcn_readlane(rel, m); // exec-independent
        bitmap |= 1ULL << rm;
    }

    // Hot path: 8 independent loads, skipping rows that will be overwritten.
    const long long base = ((long long)b * kN + row0) * kC4;
    f4 v[ITEMS];
#pragma unroll
    for (int k = 0; k < ITEMS; ++k) {
        const int r = (tid + k * 256) >> 5;               // this item's row
        if (!((bitmap >> r) & 1ULL)) {
            v[k] = src[base + tid + k * 256];
        }
    }

    // Rare path: indexed rows get the accumulated tar sum.
    const f4* tb = tar + (long long)b * kM * kC4;
    const int c4 = tid & (kC4 - 1);
#pragma unroll
    for (int k = 0; k < ITEMS; ++k) {
        const int r = (tid + k * 256) >> 5;
        if ((bitmap >> r) & 1ULL) {
            const int n = row0 + r;
            f4 acc = {0.f, 0.f, 0.f, 0.f};
            for (unsigned long long mm = lmask; mm; mm &= mm - 1) {
                const int m = (int)__builtin_ctzll(mm);
                const int t = __builtin_amdgcn_readlane(my_idx, m); // safe in divergence
                if (t == n) acc += tb[m * kC4 + c4];
            }
            v[k] = acc;
        }
    }

    // Stores: coalesced; overlap remaining loads via counted vmcnt.
#pragma unroll
    for (int k = 0; k < ITEMS; ++k) {
        out[base + tid + k * 256] = v[k];
    }
}

extern "C" void kernel_launch(void* const* d_in, const int* in_sizes, int n_in,
                              void* d_out, int out_size, void* d_ws, size_t ws_size,
                              hipStream_t stream) {
    const f4*  src     = (const f4*)d_in[0];
    const f4*  tar     = (const f4*)d_in[1];
    const int* indices = (const int*)d_in[2];
    f4*        out     = (f4*)d_out;

    eag_fused<<<kB * BPB, 256, 0, stream>>>(src, tar, indices, out);
}

// Round 7
// 389.122 us; speedup vs baseline: 1.7206x; 1.7206x over previous
//
#include <hip/hip_runtime.h>

// Problem constants (from reference): B=2048, N=1024, C=128, M=64
constexpr int kB  = 2048;
constexpr int kN  = 1024;
constexpr int kC  = 128;
constexpr int kM  = 64;
constexpr int kC4 = kC / 4;    // float4 chunks per row = 32

constexpr int RPB   = 64;            // rows per block (== 64 -> u64 bitmap)
constexpr int BPB   = kN / RPB;      // row-blocks per batch = 16
constexpr int ITEMS = RPB * kC4 / 256;  // float4 items per thread = 8

using f4 = __attribute__((ext_vector_type(4))) float;

// ---------------------------------------------------------------------------
// Fused erase-add gate — barrier-free, LDS-free.
// One block = 64 rows of one batch; each wave fully independent:
//  - lane m holds indices[b][m]; ballot -> SGPR mask of locally-landing slots;
//  - short uniform loop (ctz + readlane) builds a u64 bitmap of indexed rows;
//  - hot path: 8 UNCONDITIONAL float4 loads (R6 lesson: predicating these
//    wrecks memory-level parallelism -> 2.3 TB/s; unconditional keeps 8
//    loads in flight), then 8 coalesced stores; no barrier -> stores overlap
//    outstanding loads via counted vmcnt;
//  - rare path (~6% of half-waves): gated by the register bitmap; walk the
//    ballot mask (avg ~4 bits), broadcast idx[m] with
//    __builtin_amdgcn_readlane (v_readlane IGNORES EXEC -> safe inside this
//    divergent branch; __shfl/bpermute is NOT). Accumulate matching tar rows
//    in slot order (duplicates sum; erase zeroes the src term).
// Every output element is written exactly once per call (deterministic).
// ---------------------------------------------------------------------------
__global__ __launch_bounds__(256) void eag_fused(const f4* __restrict__ src,
                                                 const f4* __restrict__ tar,
                                                 const int* __restrict__ indices,
                                                 f4* __restrict__ out) {
    const int bid  = blockIdx.x;
    const int b    = bid >> 4;                 // / BPB
    const int row0 = (bid & (BPB - 1)) * RPB;
    const int tid  = threadIdx.x;
    const int lane = tid & 63;

    // Hot path first: 8 independent 16B loads in flight immediately.
    const long long base = ((long long)b * kN + row0) * kC4;
    f4 v[ITEMS];
#pragma unroll
    for (int k = 0; k < ITEMS; ++k) {
        v[k] = src[base + tid + k * 256];
    }

    // Per-wave index bookkeeping, register-resident (overlaps the loads).
    const int my_idx = indices[b * kM + lane];
    const int rel    = my_idx - row0;
    const bool local = (rel >= 0) && (rel < RPB);
    const unsigned long long lmask = __ballot(local);

    // Row bitmap (bit r = row row0+r is indexed): uniform loop, all lanes on.
    unsigned long long bitmap = 0;
    for (unsigned long long mm = lmask; mm; mm &= mm - 1) {
        const int m  = (int)__builtin_ctzll(mm);          // uniform slot id
        const int rm = __builtin_amdgcn_readlane(rel, m); // exec-independent
        bitmap |= 1ULL << rm;
    }

    // Rare path: indexed rows get the accumulated tar sum instead.
    const f4* tb = tar + (long long)b * kM * kC4;
    const int c4 = tid & (kC4 - 1);
#pragma unroll
    for (int k = 0; k < ITEMS; ++k) {
        const int r = (tid + k * 256) >> 5;               // this item's row
        if ((bitmap >> r) & 1ULL) {
            const int n = row0 + r;
            f4 acc = {0.f, 0.f, 0.f, 0.f};
            for (unsigned long long mm = lmask; mm; mm &= mm - 1) {
                const int m = (int)__builtin_ctzll(mm);
                const int t = __builtin_amdgcn_readlane(my_idx, m); // exec-safe
                if (t == n) acc += tb[m * kC4 + c4];
            }
            v[k] = acc;
        }
    }

    // Stores: coalesced; overlap remaining loads via counted vmcnt.
#pragma unroll
    for (int k = 0; k < ITEMS; ++k) {
        out[base + tid + k * 256] = v[k];
    }
}

extern "C" void kernel_launch(void* const* d_in, const int* in_sizes, int n_in,
                              void* d_out, int out_size, void* d_ws, size_t ws_size,
                              hipStream_t stream) {
    const f4*  src     = (const f4*)d_in[0];
    const f4*  tar     = (const f4*)d_in[1];
    const int* indices = (const int*)d_in[2];
    f4*        out     = (f4*)d_out;

    eag_fused<<<kB * BPB, 256, 0, stream>>>(src, tar, indices, out);
}

// Round 8
// 379.098 us; speedup vs baseline: 1.7661x; 1.0264x over previous
//
#include <hip/hip_runtime.h>

// Problem constants (from reference): B=2048, N=1024, C=128, M=64
constexpr int kB  = 2048;
constexpr int kN  = 1024;
constexpr int kC  = 128;
constexpr int kM  = 64;
constexpr int kC4 = kC / 4;    // float4 chunks per row = 32

constexpr int RPB   = 64;            // rows per block (== 64 -> u64 bitmap)
constexpr int BPB   = kN / RPB;      // row-blocks per batch = 16
constexpr int ITEMS = RPB * kC4 / 256;  // float4 items per thread = 8

using f4 = __attribute__((ext_vector_type(4))) float;

// ---------------------------------------------------------------------------
// Fused erase-add gate — barrier-free, LDS-free. (R7 structure + NT stores.)
//  - hot path: 8 UNCONDITIONAL float4 loads (R6 lesson: predicating loads
//    wrecks MLP -> 2.3 TB/s), then 8 coalesced NONTEMPORAL stores (out is
//    touch-once; nt skips L2 write-allocate so L2 serves the read stream);
//  - rare path (~6% of half-waves): gated by a register u64 bitmap of
//    indexed rows; walk the ballot mask (avg ~4 bits) broadcasting idx[m]
//    with __builtin_amdgcn_readlane (v_readlane ignores EXEC -> safe in the
//    divergent branch; __shfl/bpermute is NOT — R5 bug). Accumulate matching
//    tar rows in slot order (duplicates sum; erase zeroes the src term).
// Every output element is written exactly once per call (deterministic).
// ---------------------------------------------------------------------------
__global__ __launch_bounds__(256) void eag_fused(const f4* __restrict__ src,
                                                 const f4* __restrict__ tar,
                                                 const int* __restrict__ indices,
                                                 f4* __restrict__ out) {
    const int bid  = blockIdx.x;
    const int b    = bid >> 4;                 // / BPB
    const int row0 = (bid & (BPB - 1)) * RPB;
    const int tid  = threadIdx.x;
    const int lane = tid & 63;

    // Hot path first: 8 independent 16B loads in flight immediately.
    const long long base = ((long long)b * kN + row0) * kC4;
    f4 v[ITEMS];
#pragma unroll
    for (int k = 0; k < ITEMS; ++k) {
        v[k] = src[base + tid + k * 256];
    }

    // Per-wave index bookkeeping, register-resident (overlaps the loads).
    const int my_idx = indices[b * kM + lane];
    const int rel    = my_idx - row0;
    const bool local = (rel >= 0) && (rel < RPB);
    const unsigned long long lmask = __ballot(local);

    // Row bitmap (bit r = row row0+r is indexed): uniform loop, all lanes on.
    unsigned long long bitmap = 0;
    for (unsigned long long mm = lmask; mm; mm &= mm - 1) {
        const int m  = (int)__builtin_ctzll(mm);          // uniform slot id
        const int rm = __builtin_amdgcn_readlane(rel, m); // exec-independent
        bitmap |= 1ULL << rm;
    }

    // Rare path: indexed rows get the accumulated tar sum instead.
    const f4* tb = tar + (long long)b * kM * kC4;
    const int c4 = tid & (kC4 - 1);
#pragma unroll
    for (int k = 0; k < ITEMS; ++k) {
        const int r = (tid + k * 256) >> 5;               // this item's row
        if ((bitmap >> r) & 1ULL) {
            const int n = row0 + r;
            f4 acc = {0.f, 0.f, 0.f, 0.f};
            for (unsigned long long mm = lmask; mm; mm &= mm - 1) {
                const int m = (int)__builtin_ctzll(mm);
                const int t = __builtin_amdgcn_readlane(my_idx, m); // exec-safe
                if (t == n) acc += tb[m * kC4 + c4];
            }
            v[k] = acc;
        }
    }

    // Stores: coalesced nontemporal; overlap remaining loads via counted vmcnt.
#pragma unroll
    for (int k = 0; k < ITEMS; ++k) {
        __builtin_nontemporal_store(v[k], out + base + tid + k * 256);
    }
}

extern "C" void kernel_launch(void* const* d_in, const int* in_sizes, int n_in,
                              void* d_out, int out_size, void* d_ws, size_t ws_size,
                              hipStream_t stream) {
    const f4*  src     = (const f4*)d_in[0];
    const f4*  tar     = (const f4*)d_in[1];
    const int* indices = (const int*)d_in[2];
    f4*        out     = (f4*)d_out;

    eag_fused<<<kB * BPB, 256, 0, stream>>>(src, tar, indices, out);
}

// Round 9
// 370.905 us; speedup vs baseline: 1.8051x; 1.0221x over previous
//
#include <hip/hip_runtime.h>

// Problem constants (from reference): B=2048, N=1024, C=128, M=64
constexpr int kB  = 2048;
constexpr int kN  = 1024;
constexpr int kC  = 128;
constexpr int kM  = 64;
constexpr int kC4 = kC / 4;    // float4 chunks per row = 32

constexpr int RPB   = 64;            // rows per block (== 64 -> u64 bitmap)
constexpr int BPB   = kN / RPB;      // row-blocks per batch = 16
constexpr int ITEMS = RPB * kC4 / 256;  // float4 items per thread = 8

using f4 = __attribute__((ext_vector_type(4))) float;

// ---------------------------------------------------------------------------
// Fused erase-add gate — barrier-free, LDS-free. (R8 structure + NT loads.)
//  - hot path: 8 UNCONDITIONAL nontemporal float4 loads (src is touch-once:
//    skip L2 allocate; R6 lesson: never predicate these — MLP dies), then 8
//    coalesced NONTEMPORAL stores (out is touch-once). L2/L3 stay reserved
//    for the genuinely-reused tar rows (32 KB/batch x 16 blocks) + indices.
//  - rare path (~6% of half-waves): gated by a register u64 bitmap of
//    indexed rows; walk the ballot mask (avg ~4 bits) broadcasting idx[m]
//    with __builtin_amdgcn_readlane (v_readlane ignores EXEC -> safe in the
//    divergent branch; __shfl/bpermute is NOT — R5 bug). Accumulate matching
//    tar rows in slot order (duplicates sum; erase zeroes the src term).
// Every output element is written exactly once per call (deterministic).
// ---------------------------------------------------------------------------
__global__ __launch_bounds__(256) void eag_fused(const f4* __restrict__ src,
                                                 const f4* __restrict__ tar,
                                                 const int* __restrict__ indices,
                                                 f4* __restrict__ out) {
    const int bid  = blockIdx.x;
    const int b    = bid >> 4;                 // / BPB
    const int row0 = (bid & (BPB - 1)) * RPB;
    const int tid  = threadIdx.x;
    const int lane = tid & 63;

    // Hot path first: 8 independent 16B NT loads in flight immediately.
    const long long base = ((long long)b * kN + row0) * kC4;
    f4 v[ITEMS];
#pragma unroll
    for (int k = 0; k < ITEMS; ++k) {
        v[k] = __builtin_nontemporal_load(src + base + tid + k * 256);
    }

    // Per-wave index bookkeeping, register-resident (overlaps the loads).
    const int my_idx = indices[b * kM + lane];
    const int rel    = my_idx - row0;
    const bool local = (rel >= 0) && (rel < RPB);
    const unsigned long long lmask = __ballot(local);

    // Row bitmap (bit r = row row0+r is indexed): uniform loop, all lanes on.
    unsigned long long bitmap = 0;
    for (unsigned long long mm = lmask; mm; mm &= mm - 1) {
        const int m  = (int)__builtin_ctzll(mm);          // uniform slot id
        const int rm = __builtin_amdgcn_readlane(rel, m); // exec-independent
        bitmap |= 1ULL << rm;
    }

    // Rare path: indexed rows get the accumulated tar sum instead.
    const f4* tb = tar + (long long)b * kM * kC4;
    const int c4 = tid & (kC4 - 1);
#pragma unroll
    for (int k = 0; k < ITEMS; ++k) {
        const int r = (tid + k * 256) >> 5;               // this item's row
        if ((bitmap >> r) & 1ULL) {
            const int n = row0 + r;
            f4 acc = {0.f, 0.f, 0.f, 0.f};
            for (unsigned long long mm = lmask; mm; mm &= mm - 1) {
                const int m = (int)__builtin_ctzll(mm);
                const int t = __builtin_amdgcn_readlane(my_idx, m); // exec-safe
                if (t == n) acc += tb[m * kC4 + c4];
            }
            v[k] = acc;
        }
    }

    // Stores: coalesced nontemporal; overlap remaining loads via counted vmcnt.
#pragma unroll
    for (int k = 0; k < ITEMS; ++k) {
        __builtin_nontemporal_store(v[k], out + base + tid + k * 256);
    }
}

extern "C" void kernel_launch(void* const* d_in, const int* in_sizes, int n_in,
                              void* d_out, int out_size, void* d_ws, size_t ws_size,
                              hipStream_t stream) {
    const f4*  src     = (const f4*)d_in[0];
    const f4*  tar     = (const f4*)d_in[1];
    const int* indices = (const int*)d_in[2];
    f4*        out     = (f4*)d_out;

    eag_fused<<<kB * BPB, 256, 0, stream>>>(src, tar, indices, out);
}